// Round 13
// baseline (722.392 us; speedup 1.0000x reference)
//
#include <hip/hip_runtime.h>
#include <hip/hip_bf16.h>
#include <stdint.h>

#define MB 8192
#define NL 16384
#define KD 768
#define TOPK 32
#define CAND_NEED 48     // exact-recompute the approx-top-48 (16-rank margin vs bf16 noise)
#define TAU 0.70f        // GEMM-epilogue nomination threshold (rank-48 stat ~0.83 +- 0.013)
#define CAP_MIN 288      // list capacity floor for the fast path (n ~ 157 +- 12.5, ~10 sigma)

typedef short bf16x8 __attribute__((ext_vector_type(8)));
typedef float f32x4 __attribute__((ext_vector_type(4)));
typedef float f32x2 __attribute__((ext_vector_type(2)));
typedef unsigned short ushort_t;

__device__ __forceinline__ short f2bf(float f) {
  unsigned u = __builtin_bit_cast(unsigned, f);
  u = (u + 0x7fffu + ((u >> 16) & 1u)) >> 16;  // RNE
  return (short)u;
}
__device__ __forceinline__ float bf2f(ushort_t u) {
  return __builtin_bit_cast(float, (unsigned)u << 16);
}

// async global->LDS, 16B per lane; LDS dest = wave-uniform base + lane*16
__device__ __forceinline__ void gload16(const ushort_t* g, short* l) {
  __builtin_amdgcn_global_load_lds(
      (const __attribute__((address_space(1))) void*)g,
      (__attribute__((address_space(3))) void*)l, 16, 0, 0);
}

// ============ f32 -> bf16 pre-conversion (16 B/thread) ============
// Tier A also folds the cnt-counter zeroing into the X pass (blocks 0-31).
__global__ __launch_bounds__(256) void cvt_bf16(const float* __restrict__ in,
                                                ushort_t* __restrict__ out, int n8,
                                                int* __restrict__ cnt0) {
  int i = blockIdx.x * 256 + threadIdx.x;
  if (cnt0 && blockIdx.x < 32) cnt0[blockIdx.x * 256 + threadIdx.x] = 0;
  if (i >= n8) return;
  const float4 v0 = *(const float4*)(in + (size_t)i * 8);
  const float4 v1 = *(const float4*)(in + (size_t)i * 8 + 4);
  bf16x8 p;
  p[0] = f2bf(v0.x); p[1] = f2bf(v0.y); p[2] = f2bf(v0.z); p[3] = f2bf(v0.w);
  p[4] = f2bf(v1.x); p[5] = f2bf(v1.y); p[6] = f2bf(v1.z); p[7] = f2bf(v1.w);
  *(bf16x8*)(out + (size_t)i * 8) = p;
}

// ============ W_dec transpose to PLAIN bf16 rows [NL][KD] ============
__global__ __launch_bounds__(256) void transpose_wdec(const float* __restrict__ W,
                                                      ushort_t* __restrict__ WT) {
  __shared__ float tile[32][33];
  int l0 = blockIdx.x * 32;
  int d0 = blockIdx.y * 32;
  int lx = threadIdx.x;  // 0..31
  for (int i = threadIdx.y; i < 32; i += 8)
    tile[i][lx] = W[(size_t)(d0 + i) * NL + (l0 + lx)];
  __syncthreads();
  for (int i = threadIdx.y; i < 32; i += 8)
    WT[(size_t)(l0 + i) * KD + (d0 + lx)] = (ushort_t)f2bf(tile[lx][i]);
}

#define GBM 128
#define GBN 128
#define GBK 32
#define LDA 32  // 64B rows, 4 x 16B slots; swizzle: phys slot s holds logical s^((row>>1)&3)

// candidate-emitting epilogue (4x4 variant, f32 fallback GEMM)
__device__ __forceinline__ void emit_cands(const f32x4 (&acc)[4][4], int m0, int n0,
                                           int wr64, int wc64, int er, int ec,
                                           int* __restrict__ cnt,
                                           unsigned* __restrict__ lists, int cap) {
#pragma unroll
  for (int i = 0; i < 4; i++)
#pragma unroll
    for (int j = 0; j < 4; j++)
#pragma unroll
      for (int r = 0; r < 4; r++) {
        float v = acc[i][j][r];
        if (v > TAU) {
          int grow = m0 + wr64 + i * 16 + er + r;
          int gcol = n0 + wc64 + j * 16 + ec;
          int pos = atomicAdd(&cnt[grow], 1);
          if (pos < cap)
            lists[(size_t)grow * cap + pos] =
                (unsigned)gcol | ((unsigned)(ushort_t)f2bf(v) << 16);
        }
      }
}

// ============ Encoder GEMM v5: 256x256 tile, 8 waves, barrier-amortized ============
// Rationale (R12 PMC: MfmaUtil 26, VALUBusy 15, Occ 38 -> sync-bound): the 128^2
// loop pays 2 barriers per 1.05 MFLOP; this pays 2 per 8.4 MFLOP (8x). Per-K-tile
// pipes: MFMA ~2500 cyc/CU > LDS-read 1536 cyc -> MFMA-bound regime (m201-class).
// Built ONLY from harness-verified pieces:
//  - K-tile stored as TWO 32-k sub-tiles, each the PROVEN [row][32] 64-B-row
//    layout with the PROVEN slot swizzle (slog/fkb formulas re-derived for 512
//    threads: identical bit patterns).
//  - staging: linear LDS dest (wave-uniform base + lane*16) + inverse-swizzled
//    source slot, verbatim.
//  - emit epilogue: R8-verified i<8 variant.
// Schedule: 2-deep prefetch; top wait vmcnt(8) (tile kt landed, kt+1 in flight,
// never 0 mid-loop); barrier; ALL 24 frag ds_reads -> regs; lgkmcnt(0) +
// sched_barrier (rule #18); barrier (all waves done reading buf cur); stage
// kt+2 into the freed buffer; setprio(1); 64 MFMA; setprio(0).
// LDS 128 KB (dynamic) -> 1 block/CU, 8 waves; latency hidden intra-block.
#define QBM 256
#define QBN 256
#define QBK 64
__global__ __launch_bounds__(512, 2) void encoder_gemm_8w(const ushort_t* __restrict__ Xb,
                                                          const ushort_t* __restrict__ Wb,
                                                          int* __restrict__ cnt,
                                                          unsigned* __restrict__ lists,
                                                          int cap) {
  extern __shared__ short smem[];
  short* As = smem;           // [2 buf][2 sub][256 rows][32]  = 64 KB
  short* Bs = smem + 32768;   // same                          = 64 KB

  const int tid = threadIdx.x;
  const int w = tid >> 6;       // 0..7
  const int lane = tid & 63;

  const int NBN = NL / QBN;            // 64
  const int GROUP = 8;
  const int NWG = (MB / QBM) * NBN;    // 2048
  const int CPX = NWG / 8;             // 256 (2048 % 8 == 0 -> bijective)
  int bid = (blockIdx.x % 8) * CPX + blockIdx.x / 8;
  int group = bid / (GROUP * NBN);
  int rem = bid % (GROUP * NBN);
  int bm = group * GROUP + (rem % GROUP);   // 0..31
  int bn = rem / GROUP;                     // 0..63
  const int m0 = bm * QBM, n0 = bn * QBN;

  // staging (proven formulas): thread t covers row t>>2 (0..127) phys slot t&3;
  // source logical slot = (t&3) ^ ((t>>3)&3); second call covers rows +128.
  const int srow = tid >> 2;                        // 0..127
  const int slog = (tid & 3) ^ ((tid >> 3) & 3);
  const ushort_t* Asrc = Xb + (size_t)(m0 + srow) * KD + slog * 8;
  const ushort_t* Bsrc = Wb + (size_t)(n0 + srow) * KD + slog * 8;

  // one K-tile = 2 sub-tiles x 2 row-halves x (A,B) = 8 gload16/thread
#define STAGEQ(BUF, KT)                                                     \
  {                                                                         \
    _Pragma("unroll")                                                       \
    for (int sb = 0; sb < 2; sb++) {                                        \
      const int ko_ = (KT) * QBK + sb * 32;                                 \
      short* la_ = As + ((BUF) * 2 + sb) * 8192 + w * 512;                  \
      short* lb_ = Bs + ((BUF) * 2 + sb) * 8192 + w * 512;                  \
      gload16(Asrc + ko_, la_);                                             \
      gload16(Asrc + (size_t)128 * KD + ko_, la_ + 4096);                   \
      gload16(Bsrc + ko_, lb_);                                             \
      gload16(Bsrc + (size_t)128 * KD + ko_, lb_ + 4096);                   \
    }                                                                       \
  }

  const int wr = (w >> 2) * 128;   // wave rows: 0 or 128
  const int wc = (w & 3) * 64;     // wave cols: 0/64/128/192
  const int fr = lane & 15;
  const int fkb = (((lane >> 4) ^ ((fr >> 1) & 3))) * 8;  // proven swizzled read

  f32x4 acc[8][4];
#pragma unroll
  for (int i = 0; i < 8; i++)
#pragma unroll
    for (int j = 0; j < 4; j++)
#pragma unroll
      for (int r = 0; r < 4; r++) acc[i][j][r] = 0.f;

  // 2-deep prologue: tiles 0 and 1 in flight (16 loads/thread)
  STAGEQ(0, 0)
  STAGEQ(1, 1)

  const int NT = KD / QBK;  // 12
  for (int kt = 0; kt < NT; kt++) {
    // tile kt's 8 loads done; tile kt+1's 8 remain in flight (counted, not 0)
    if (kt + 1 < NT) {
      asm volatile("s_waitcnt vmcnt(8)" ::: "memory");
    } else {
      asm volatile("s_waitcnt vmcnt(0)" ::: "memory");
    }
    __builtin_amdgcn_s_barrier();

    const int cur = kt & 1;
    bf16x8 af[8][2], bg[4][2];
#pragma unroll
    for (int sb = 0; sb < 2; sb++) {
      const short* Ab = As + (cur * 2 + sb) * 8192;
      const short* Bb = Bs + (cur * 2 + sb) * 8192;
#pragma unroll
      for (int i = 0; i < 8; i++)
        af[i][sb] = *(const bf16x8*)(Ab + (wr + i * 16 + fr) * 32 + fkb);
#pragma unroll
      for (int j = 0; j < 4; j++)
        bg[j][sb] = *(const bf16x8*)(Bb + (wc + j * 16 + fr) * 32 + fkb);
    }
    // all frags in regs before any wave overwrites buf cur (rule #18 fence)
    asm volatile("s_waitcnt lgkmcnt(0)" ::: "memory");
    __builtin_amdgcn_sched_barrier(0);
    __builtin_amdgcn_s_barrier();
    if (kt + 2 < NT) STAGEQ(cur, kt + 2)  // overwrite the just-freed buffer

    __builtin_amdgcn_s_setprio(1);
#pragma unroll
    for (int sb = 0; sb < 2; sb++)
#pragma unroll
      for (int i = 0; i < 8; i++)
#pragma unroll
        for (int j = 0; j < 4; j++)
          acc[i][j] = __builtin_amdgcn_mfma_f32_16x16x32_bf16(af[i][sb], bg[j][sb],
                                                              acc[i][j], 0, 0, 0);
    __builtin_amdgcn_s_setprio(0);
  }

  // epilogue (R8-verified): C frag col=lane&15, row=(lane>>4)*4+r
  const int er = (lane >> 4) * 4;
  const int ec = lane & 15;
#pragma unroll
  for (int i = 0; i < 8; i++)
#pragma unroll
    for (int j = 0; j < 4; j++)
#pragma unroll
      for (int r = 0; r < 4; r++) {
        float v = acc[i][j][r];
        if (v > TAU) {
          int grow = m0 + wr + i * 16 + er + r;
          int gcol = n0 + wc + j * 16 + ec;
          int pos = atomicAdd(&cnt[grow], 1);
          if (pos < cap)
            lists[(size_t)grow * cap + pos] =
                (unsigned)gcol | ((unsigned)(ushort_t)f2bf(v) << 16);
        }
      }
#undef STAGEQ
}

// ============ Encoder GEMM, f32 inputs w/ inline cvt (fallback if ws too small) ============
__global__ __launch_bounds__(256, 4) void encoder_gemm_f32(const float* __restrict__ X,
                                                           const float* __restrict__ Wenc,
                                                           int* __restrict__ cnt,
                                                           unsigned* __restrict__ lists,
                                                           int cap) {
  __shared__ short Al[2][GBM][LDA];
  __shared__ short Bl[2][GBN][LDA];

  const int tid = threadIdx.x;
  const int NBN = NL / GBN;
  const int GROUP = 8;
  int bid = blockIdx.x;
  int group = bid / (GROUP * NBN);
  int rem = bid % (GROUP * NBN);
  int bm = group * GROUP + (rem % GROUP);
  int bn = rem / GROUP;
  const int m0 = bm * GBM, n0 = bn * GBN;

  const int srow = tid >> 2;
  const int skg = tid & 3;
  const int sw8 = (skg ^ ((srow >> 1) & 3)) * 8;

  const float* Abase = X + (size_t)(m0 + srow) * KD + skg * 8;
  const float* Bbase = Wenc + (size_t)(n0 + srow) * KD + skg * 8;

  float4 ra0, ra1, ra2, ra3, rb0, rb1, rb2, rb3;

#define FLOADS(KT)                                         \
  {                                                        \
    const float* ap_ = Abase + (KT) * GBK;                 \
    const float* bp_ = Bbase + (KT) * GBK;                 \
    ra0 = *(const float4*)(ap_);                           \
    ra1 = *(const float4*)(ap_ + 4);                       \
    ra2 = *(const float4*)(ap_ + (size_t)64 * KD);         \
    ra3 = *(const float4*)(ap_ + (size_t)64 * KD + 4);     \
    rb0 = *(const float4*)(bp_);                           \
    rb1 = *(const float4*)(bp_ + 4);                       \
    rb2 = *(const float4*)(bp_ + (size_t)64 * KD);         \
    rb3 = *(const float4*)(bp_ + (size_t)64 * KD + 4);     \
  }

#define CVT8(DST, FA, FB)                                                    \
  {                                                                          \
    bf16x8 p_;                                                               \
    p_[0] = f2bf(FA.x); p_[1] = f2bf(FA.y); p_[2] = f2bf(FA.z);              \
    p_[3] = f2bf(FA.w); p_[4] = f2bf(FB.x); p_[5] = f2bf(FB.y);              \
    p_[6] = f2bf(FB.z); p_[7] = f2bf(FB.w);                                  \
    *(bf16x8*)(DST) = p_;                                                    \
  }

#define FWRITE(BUF)                                      \
  {                                                      \
    CVT8(&Al[BUF][srow][sw8], ra0, ra1);                 \
    CVT8(&Al[BUF][srow + 64][sw8], ra2, ra3);            \
    CVT8(&Bl[BUF][srow][sw8], rb0, rb1);                 \
    CVT8(&Bl[BUF][srow + 64][sw8], rb2, rb3);            \
  }

  const int lane = tid & 63;
  const int w = tid >> 6;
  const int wr64 = (w >> 1) * 64;
  const int wc64 = (w & 1) * 64;
  const int fr = lane & 15;
  const int fkb_sw = (((lane >> 4) ^ ((fr >> 1) & 3))) * 8;

  f32x4 acc[4][4];
#pragma unroll
  for (int i = 0; i < 4; i++)
#pragma unroll
    for (int j = 0; j < 4; j++)
#pragma unroll
      for (int r = 0; r < 4; r++) acc[i][j][r] = 0.f;

  FLOADS(0);
  FWRITE(0);
  __syncthreads();

  const int NT = KD / GBK;
  for (int kt = 0; kt < NT; kt++) {
    const int cur = kt & 1;
    if (kt + 1 < NT) FLOADS(kt + 1);

    bf16x8 af[4], bg[4];
#pragma unroll
    for (int i = 0; i < 4; i++)
      af[i] = *(const bf16x8*)&Al[cur][wr64 + i * 16 + fr][fkb_sw];
#pragma unroll
    for (int j = 0; j < 4; j++)
      bg[j] = *(const bf16x8*)&Bl[cur][wc64 + j * 16 + fr][fkb_sw];

#pragma unroll
    for (int i = 0; i < 4; i++)
#pragma unroll
      for (int j = 0; j < 4; j++)
        acc[i][j] = __builtin_amdgcn_mfma_f32_16x16x32_bf16(af[i], bg[j], acc[i][j], 0, 0, 0);

    if (kt + 1 < NT) FWRITE(cur ^ 1);
    __syncthreads();
  }

  const int er = (lane >> 4) * 4;
  const int ec = lane & 15;
  emit_cands(acc, m0, n0, wr64, wc64, er, ec, cnt, lists, cap);
#undef FLOADS
#undef CVT8
#undef FWRITE
}

// ============ Select + decode, WAVE-PER-ROW + key-packed narrow (R12, banked) ====
__global__ __launch_bounds__(256) void select_decode(const int* __restrict__ cnt,
                                                     const unsigned* __restrict__ lists,
                                                     int cap,
                                                     const float* __restrict__ X,
                                                     const float* __restrict__ Wenc,
                                                     const ushort_t* __restrict__ WdTb,
                                                     const float* __restrict__ Wdec,
                                                     int use_wdt,
                                                     float* __restrict__ Z,
                                                     float* __restrict__ Xhat) {
  __shared__ float xrow[4][KD];
  __shared__ unsigned keys[4][512];
  __shared__ int s48_j[4][CAND_NEED];
  __shared__ float s48_v[4][CAND_NEED];
  __shared__ int sel_j[4][TOPK];
  __shared__ float sel_v[4][TOPK];

  const int tid = threadIdx.x;
  const int w = tid >> 6;
  const int lane = tid & 63;
  const int row = blockIdx.x * 4 + w;
  float* z = Z + (size_t)row * NL;

  // xrow load: 768 floats = 3 float4 per lane, coalesced
  {
    const float4* xs = (const float4*)(X + (size_t)row * KD);
    float4* xd = (float4*)xrow[w];
#pragma unroll
    for (int q = 0; q < 3; q++) xd[lane + 64 * q] = xs[lane + 64 * q];
  }

  const int n = cnt[row];
  const bool fb = (n < CAND_NEED) || (n > cap) || (n > 512);

  if (!fb) {
    for (int i = lane; i < n; i += 64)
      keys[w][i] = lists[(size_t)row * cap + i] ^ 0xFFFFu;
    // narrow: rank by key desc (== value desc, index asc); keep ranks < 48
    for (int i = lane; i < n; i += 64) {
      unsigned ki = keys[w][i];
      int r = 0;
      for (int c = 0; c < n; c++) r += (int)(keys[w][c] > ki);
      if (r < CAND_NEED) s48_j[w][r] = (int)((~ki) & 0xFFFFu);
    }
    // exact f32 recompute: ONE LANE per candidate, sequential k=0..767 fmaf
    // (bit-identical rounding chain — certified; DO NOT REORDER)
    if (lane < CAND_NEED) {
      const float4* wr4 = (const float4*)(Wenc + (size_t)s48_j[w][lane] * KD);
      float s = 0.f;
#pragma unroll 8
      for (int k4 = 0; k4 < KD / 4; k4++) {
        float4 wv = wr4[k4];
        s = fmaf(xrow[w][4 * k4 + 0], wv.x, s);
        s = fmaf(xrow[w][4 * k4 + 1], wv.y, s);
        s = fmaf(xrow[w][4 * k4 + 2], wv.z, s);
        s = fmaf(xrow[w][4 * k4 + 3], wv.w, s);
      }
      s48_v[w][lane] = s;
    }
    // z-zero, whole wave, non-temporal (never re-read)
    {
      const f32x4 zf = {0.f, 0.f, 0.f, 0.f};
      f32x4* z4 = (f32x4*)z;
      for (int i = lane; i < NL / 4; i += 64)
        __builtin_nontemporal_store(zf, z4 + i);
    }
    // exact top-32 by (value desc, index asc)
    if (lane < CAND_NEED) {
      float vi = s48_v[w][lane];
      int ji = s48_j[w][lane];
      int r = 0;
      for (int c = 0; c < CAND_NEED; c++) {
        float vc = s48_v[w][c];
        r += (int)((vc > vi) || (vc == vi && s48_j[w][c] < ji));
      }
      if (r < TOPK) { sel_j[w][r] = ji; sel_v[w][r] = fmaxf(vi, 0.f); }
    }
    // drain z-zero stores before scattering winners into the same row
    asm volatile("s_waitcnt vmcnt(0)" ::: "memory");
    if (lane < TOPK) z[sel_j[w][lane]] = sel_v[w][lane];
  } else {
    // ---- rare exact fallback (n stats make this ~never): dense per-wave
    for (int j = lane; j < NL; j += 64) {
      const float* wr = Wenc + (size_t)j * KD;
      float s = 0.f;
      for (int k = 0; k < KD; k++) s = fmaf(xrow[w][k], wr[k], s);
      z[j] = fmaxf(s, 0.f);
    }
    asm volatile("s_waitcnt vmcnt(0)" ::: "memory");
    for (int t = 0; t < TOPK; t++) {
      float bm = -1.f;
      int bi = NL;
      for (int j = lane; j < NL; j += 64) {
        float v = z[j];
        if (v > bm || (v == bm && j < bi)) { bm = v; bi = j; }
      }
#pragma unroll
      for (int off = 32; off > 0; off >>= 1) {
        float vo = __shfl_down(bm, off);
        int io = __shfl_down(bi, off);
        if (vo > bm || (vo == bm && io < bi)) { bm = vo; bi = io; }
      }
      bm = __shfl(bm, 0);
      bi = __shfl(bi, 0);
      if (lane == 0) {
        sel_j[w][t] = bi;
        sel_v[w][t] = bm;
        z[bi] = -1.f;  // sentinel below any relu'd value
      }
      asm volatile("s_waitcnt vmcnt(0)" ::: "memory");
    }
    for (int j = lane; j < NL; j += 64) z[j] = 0.f;
    asm volatile("s_waitcnt vmcnt(0)" ::: "memory");
    if (lane < TOPK) z[sel_j[w][lane]] = sel_v[w][lane];
  }

  // ---- fused decode, per-wave: lane owns 12 outputs d = q*128 + lane*2 (+1)
  float alo[6], ahi[6];
#pragma unroll
  for (int q = 0; q < 6; q++) { alo[q] = 0.f; ahi[q] = 0.f; }
  if (use_wdt) {
    for (int t = 0; t < TOPK; t++) {
      float v = sel_v[w][t];
      const unsigned* wr = (const unsigned*)(WdTb + (size_t)sel_j[w][t] * KD);
#pragma unroll
      for (int q = 0; q < 6; q++) {
        unsigned u = wr[q * 64 + lane];
        alo[q] = fmaf(v, bf2f((ushort_t)(u & 0xffffu)), alo[q]);
        ahi[q] = fmaf(v, bf2f((ushort_t)(u >> 16)), ahi[q]);
      }
    }
  } else {
    for (int t = 0; t < TOPK; t++) {
      float v = sel_v[w][t];
      const float* wc = Wdec + sel_j[w][t];
#pragma unroll
      for (int q = 0; q < 6; q++) {
        int d = q * 128 + lane * 2;
        alo[q] = fmaf(v, wc[(size_t)d * NL], alo[q]);
        ahi[q] = fmaf(v, wc[(size_t)(d + 1) * NL], ahi[q]);
      }
    }
  }
  float* xo = Xhat + (size_t)row * KD;
#pragma unroll
  for (int q = 0; q < 6; q++) {
    f32x2 st = {alo[q], ahi[q]};
    __builtin_nontemporal_store(st, (f32x2*)(xo + q * 128 + lane * 2));
  }
}

// ============ launch ============
extern "C" void kernel_launch(void* const* d_in, const int* in_sizes, int n_in,
                              void* d_out, int out_size, void* d_ws, size_t ws_size,
                              hipStream_t stream) {
  const float* x = (const float*)d_in[0];
  const float* Wenc = (const float*)d_in[1];
  const float* Wdec = (const float*)d_in[2];
  // d_in[3] is k (always 32 for this problem)

  float* xhat = (float*)d_out;
  float* z = (float*)d_out + (size_t)MB * KD;

  const size_t cnt_b = (size_t)MB * sizeof(int);              // 32 KB
  const size_t wsh_b = (size_t)NL * KD * sizeof(ushort_t);    // 25.2 MB (Wb, then WdTb)
  const size_t xb_b = (size_t)MB * KD * sizeof(ushort_t);     // 12.6 MB
  const size_t entry = sizeof(unsigned);                      // 4 B packed list entries

  char* ws = (char*)d_ws;
  int* cnt = (int*)ws;
  size_t off = cnt_b;

  int use_pre = 0, use_wdt = 0, cap = 1;
  ushort_t* Wsh = nullptr;
  ushort_t* Xb = nullptr;
  unsigned* lists = nullptr;

  if (ws_size >= cnt_b + wsh_b + xb_b + (size_t)MB * entry * CAP_MIN) {
    // tier A: bf16 global_load_lds GEMM; Wsh time-shared (Wb during GEMM, WdTb after)
    use_pre = 1; use_wdt = 1;
    Wsh = (ushort_t*)(ws + off); off += wsh_b;
    Xb = (ushort_t*)(ws + off); off += xb_b;
    lists = (unsigned*)(ws + off);
    size_t c = (ws_size - off) / ((size_t)MB * entry);
    cap = (int)(c > 512 ? 512 : c);
  } else if (ws_size >= cnt_b + wsh_b + (size_t)MB * entry * CAP_MIN) {
    // tier B: f32 GEMM with inline cvt; plain WdTb decode
    use_wdt = 1;
    Wsh = (ushort_t*)(ws + off); off += wsh_b;
    lists = (unsigned*)(ws + off);
    size_t c = (ws_size - off) / ((size_t)MB * entry);
    cap = (int)(c > 512 ? 512 : c);
  } else {
    // tier C: degraded — strided Wdec decode; whatever list fits (fb catches overflow)
    lists = (unsigned*)(ws + off);
    size_t avail = (ws_size > off) ? (ws_size - off) : 0;
    size_t c = avail / ((size_t)MB * entry);
    cap = (int)(c > 512 ? 512 : c);
    if (cap < 1) cap = 1;
  }

  if (use_pre) {
    // 128 KB dynamic LDS for the 8-wave GEMM (idempotent, host-side, capture-safe)
    static bool attr_set = false;
    if (!attr_set) {
      hipFuncSetAttribute((const void*)encoder_gemm_8w,
                          hipFuncAttributeMaxDynamicSharedMemorySize, 131072);
      attr_set = true;
    }
    // cnt zeroing folded into the X cvt (blocks 0-31)
    int nx8 = MB * KD / 8, nw8 = NL * KD / 8;
    cvt_bf16<<<(nx8 + 255) / 256, 256, 0, stream>>>(x, Xb, nx8, cnt);
    cvt_bf16<<<(nw8 + 255) / 256, 256, 0, stream>>>(Wenc, Wsh, nw8, nullptr);
    encoder_gemm_8w<<<(MB / QBM) * (NL / QBN), 512, 131072, stream>>>(Xb, Wsh, cnt,
                                                                      lists, cap);
    // transpose AFTER the GEMM: Wsh is reused (stream-serialized, so no race)
    dim3 g(NL / 32, KD / 32);
    transpose_wdec<<<g, dim3(32, 8), 0, stream>>>(Wdec, Wsh);
  } else {
    hipMemsetAsync(cnt, 0, cnt_b, stream);
    if (use_wdt) {
      dim3 g(NL / 32, KD / 32);
      transpose_wdec<<<g, dim3(32, 8), 0, stream>>>(Wdec, Wsh);
    }
    encoder_gemm_f32<<<(MB / GBM) * (NL / GBN), 256, 0, stream>>>(x, Wenc, cnt, lists, cap);
  }
  select_decode<<<MB / 4, 256, 0, stream>>>(cnt, lists, cap, x, Wenc, Wsh, Wdec, use_wdt,
                                            z, xhat);
}

// Round 14
// 594.393 us; speedup vs baseline: 1.2153x; 1.2153x over previous
//
#include <hip/hip_runtime.h>
#include <hip/hip_bf16.h>
#include <stdint.h>

#define MB 8192
#define NL 16384
#define KD 768
#define TOPK 32
#define CAND_NEED 40     // exact-recompute approx-top-40 (rank-32->40 margin ~0.022 >> ~0.003 bf16-path noise)
#define TAU 0.70f        // GEMM-epilogue nomination threshold (rank-48 stat ~0.83 +- 0.013)
#define CAP_MIN 288      // list capacity floor for the fast path (n ~ 157 +- 12.5, ~10 sigma)

typedef short bf16x8 __attribute__((ext_vector_type(8)));
typedef float f32x4 __attribute__((ext_vector_type(4)));
typedef float f32x2 __attribute__((ext_vector_type(2)));
typedef unsigned short ushort_t;

__device__ __forceinline__ short f2bf(float f) {
  unsigned u = __builtin_bit_cast(unsigned, f);
  u = (u + 0x7fffu + ((u >> 16) & 1u)) >> 16;  // RNE
  return (short)u;
}
__device__ __forceinline__ float bf2f(ushort_t u) {
  return __builtin_bit_cast(float, (unsigned)u << 16);
}

// async global->LDS, 16B per lane; LDS dest = wave-uniform base + lane*16
__device__ __forceinline__ void gload16(const ushort_t* g, short* l) {
  __builtin_amdgcn_global_load_lds(
      (const __attribute__((address_space(1))) void*)g,
      (__attribute__((address_space(3))) void*)l, 16, 0, 0);
}

// ============ fused f32 -> bf16 pre-conversion for X and Wenc (one dispatch) ============
// blocks [0, nx8/256) convert X; the rest convert Wenc; blocks 0-31 also zero cnt.
__global__ __launch_bounds__(256) void cvt_both(const float* __restrict__ xin,
                                                ushort_t* __restrict__ xout, int nx8,
                                                const float* __restrict__ win,
                                                ushort_t* __restrict__ wout, int nw8,
                                                int* __restrict__ cnt0) {
  const int b = blockIdx.x;
  if (b < 32) cnt0[b * 256 + threadIdx.x] = 0;
  const int nxb = nx8 / 256;  // 3072 (exact)
  const float* in;
  ushort_t* out;
  int i;
  if (b < nxb) {
    i = b * 256 + threadIdx.x;
    if (i >= nx8) return;
    in = xin; out = xout;
  } else {
    i = (b - nxb) * 256 + threadIdx.x;
    if (i >= nw8) return;
    in = win; out = wout;
  }
  const float4 v0 = *(const float4*)(in + (size_t)i * 8);
  const float4 v1 = *(const float4*)(in + (size_t)i * 8 + 4);
  bf16x8 p;
  p[0] = f2bf(v0.x); p[1] = f2bf(v0.y); p[2] = f2bf(v0.z); p[3] = f2bf(v0.w);
  p[4] = f2bf(v1.x); p[5] = f2bf(v1.y); p[6] = f2bf(v1.z); p[7] = f2bf(v1.w);
  *(bf16x8*)(out + (size_t)i * 8) = p;
}

// ============ W_dec transpose to PLAIN bf16 rows [NL][KD] ============
__global__ __launch_bounds__(256) void transpose_wdec(const float* __restrict__ W,
                                                      ushort_t* __restrict__ WT) {
  __shared__ float tile[32][33];
  int l0 = blockIdx.x * 32;
  int d0 = blockIdx.y * 32;
  int lx = threadIdx.x;  // 0..31
  for (int i = threadIdx.y; i < 32; i += 8)
    tile[i][lx] = W[(size_t)(d0 + i) * NL + (l0 + lx)];
  __syncthreads();
  for (int i = threadIdx.y; i < 32; i += 8)
    WT[(size_t)(l0 + i) * KD + (d0 + lx)] = (ushort_t)f2bf(tile[lx][i]);
}

#define GBM 128
#define GBN 128
#define GBK 32
#define LDA 32  // 64B rows, 4 x 16B slots; swizzle: phys slot s holds logical s^((row>>1)&3)

// candidate-emitting epilogue (shared by GEMM variants)
__device__ __forceinline__ void emit_cands(const f32x4 (&acc)[4][4], int m0, int n0,
                                           int wr64, int wc64, int er, int ec,
                                           int* __restrict__ cnt,
                                           unsigned* __restrict__ lists, int cap) {
#pragma unroll
  for (int i = 0; i < 4; i++)
#pragma unroll
    for (int j = 0; j < 4; j++)
#pragma unroll
      for (int r = 0; r < 4; r++) {
        float v = acc[i][j][r];
        if (v > TAU) {
          int grow = m0 + wr64 + i * 16 + er + r;
          int gcol = n0 + wc64 + j * 16 + ec;
          int pos = atomicAdd(&cnt[grow], 1);
          if (pos < cap)
            lists[(size_t)grow * cap + pos] =
                (unsigned)gcol | ((unsigned)(ushort_t)f2bf(v) << 16);
        }
      }
}

// ============ Encoder GEMM (exact R12/R7: banked best, ~342 us) ============
// 2-deep prefetch, counted vmcnt(4) at loop top (tile kt landed, kt+1 in
// flight — drains to 0 only on the last tile), raw s_barrier pair, stage
// kt+2 into the just-freed buffer. 4 blocks/CU.
// NOTE (R13/R14 post-mortems): the 2-barrier structure is FORCED at 2 buffers
// (barrier#1 = cross-wave DMA completeness, barrier#2 = overwrite protection;
// single-barrier variants race; 3-4 buffers lose the occupancy that dominates
// — R6/R8/R9/R13 all measured slower). This is the session's GEMM plateau.
__global__ __launch_bounds__(256, 4) void encoder_gemm_pre2(const ushort_t* __restrict__ Xb,
                                                            const ushort_t* __restrict__ Wb,
                                                            int* __restrict__ cnt,
                                                            unsigned* __restrict__ lists,
                                                            int cap) {
  __shared__ short Al[2][GBM][LDA];
  __shared__ short Bl[2][GBN][LDA];

  const int tid = threadIdx.x;
  const int NBN = NL / GBN;   // 128
  const int GROUP = 8;
  const int NWG = (MB / GBM) * NBN;  // 8192
  const int CPX = NWG / 8;           // 1024 (8192 % 8 == 0 -> bijective)
  int bid = (blockIdx.x % 8) * CPX + blockIdx.x / 8;
  int group = bid / (GROUP * NBN);
  int rem = bid % (GROUP * NBN);
  int bm = group * GROUP + (rem % GROUP);
  int bn = rem / GROUP;
  const int m0 = bm * GBM, n0 = bn * GBN;

  const int srow = tid >> 2;                        // 0..63
  const int slog = (tid & 3) ^ ((tid >> 3) & 3);    // inverse-swizzled source slot
  const int w = tid >> 6;

  const ushort_t* Asrc = Xb + (size_t)(m0 + srow) * KD + slog * 8;
  const ushort_t* Bsrc = Wb + (size_t)(n0 + srow) * KD + slog * 8;

#define STAGE(BUF, KT)                                              \
  {                                                                 \
    const int koff_ = (KT) * GBK;                                   \
    short* la_ = &Al[BUF][0][0] + w * 512;                          \
    short* lb_ = &Bl[BUF][0][0] + w * 512;                          \
    gload16(Asrc + koff_, la_);                                     \
    gload16(Asrc + (size_t)64 * KD + koff_, la_ + 2048);            \
    gload16(Bsrc + koff_, lb_);                                     \
    gload16(Bsrc + (size_t)64 * KD + koff_, lb_ + 2048);            \
  }

  const int lane = tid & 63;
  const int wr64 = (w >> 1) * 64;
  const int wc64 = (w & 1) * 64;
  const int fr = lane & 15;
  const int fkb_sw = (((lane >> 4) ^ ((fr >> 1) & 3))) * 8;

  f32x4 acc[4][4];
#pragma unroll
  for (int i = 0; i < 4; i++)
#pragma unroll
    for (int j = 0; j < 4; j++)
#pragma unroll
      for (int r = 0; r < 4; r++) acc[i][j][r] = 0.f;

  // 2-deep prologue: tiles 0 and 1 in flight (8 loads/thread)
  STAGE(0, 0);
  STAGE(1, 1);

  const int NT = KD / GBK;  // 24
  for (int kt = 0; kt < NT; kt++) {
    // tile kt's 4 loads done; tile kt+1's 4 remain in flight (counted, not 0)
    if (kt + 1 < NT) {
      asm volatile("s_waitcnt vmcnt(4)" ::: "memory");
    } else {
      asm volatile("s_waitcnt vmcnt(0)" ::: "memory");
    }
    __builtin_amdgcn_s_barrier();

    const int cur = kt & 1;
    bf16x8 af[4], bg[4];
#pragma unroll
    for (int i = 0; i < 4; i++)
      af[i] = *(const bf16x8*)&Al[cur][wr64 + i * 16 + fr][fkb_sw];
#pragma unroll
    for (int j = 0; j < 4; j++)
      bg[j] = *(const bf16x8*)&Bl[cur][wc64 + j * 16 + fr][fkb_sw];

#pragma unroll
    for (int i = 0; i < 4; i++)
#pragma unroll
      for (int j = 0; j < 4; j++)
        acc[i][j] = __builtin_amdgcn_mfma_f32_16x16x32_bf16(af[i], bg[j], acc[i][j], 0, 0, 0);

    // all waves' ds_reads of buf[cur] are complete (consumed by MFMAs above)
    __builtin_amdgcn_s_barrier();
    if (kt + 2 < NT) STAGE(cur, kt + 2);  // overwrite the just-freed buffer
  }

  const int er = (lane >> 4) * 4;
  const int ec = lane & 15;
  emit_cands(acc, m0, n0, wr64, wc64, er, ec, cnt, lists, cap);
#undef STAGE
}

// ============ Encoder GEMM, f32 inputs w/ inline cvt (fallback if ws too small) ============
__global__ __launch_bounds__(256, 4) void encoder_gemm_f32(const float* __restrict__ X,
                                                           const float* __restrict__ Wenc,
                                                           int* __restrict__ cnt,
                                                           unsigned* __restrict__ lists,
                                                           int cap) {
  __shared__ short Al[2][GBM][LDA];
  __shared__ short Bl[2][GBN][LDA];

  const int tid = threadIdx.x;
  const int NBN = NL / GBN;
  const int GROUP = 8;
  int bid = blockIdx.x;
  int group = bid / (GROUP * NBN);
  int rem = bid % (GROUP * NBN);
  int bm = group * GROUP + (rem % GROUP);
  int bn = rem / GROUP;
  const int m0 = bm * GBM, n0 = bn * GBN;

  const int srow = tid >> 2;
  const int skg = tid & 3;
  const int sw8 = (skg ^ ((srow >> 1) & 3)) * 8;

  const float* Abase = X + (size_t)(m0 + srow) * KD + skg * 8;
  const float* Bbase = Wenc + (size_t)(n0 + srow) * KD + skg * 8;

  float4 ra0, ra1, ra2, ra3, rb0, rb1, rb2, rb3;

#define FLOADS(KT)                                         \
  {                                                        \
    const float* ap_ = Abase + (KT) * GBK;                 \
    const float* bp_ = Bbase + (KT) * GBK;                 \
    ra0 = *(const float4*)(ap_);                           \
    ra1 = *(const float4*)(ap_ + 4);                       \
    ra2 = *(const float4*)(ap_ + (size_t)64 * KD);         \
    ra3 = *(const float4*)(ap_ + (size_t)64 * KD + 4);     \
    rb0 = *(const float4*)(bp_);                           \
    rb1 = *(const float4*)(bp_ + 4);                       \
    rb2 = *(const float4*)(bp_ + (size_t)64 * KD);         \
    rb3 = *(const float4*)(bp_ + (size_t)64 * KD + 4);     \
  }

#define CVT8(DST, FA, FB)                                                    \
  {                                                                          \
    bf16x8 p_;                                                               \
    p_[0] = f2bf(FA.x); p_[1] = f2bf(FA.y); p_[2] = f2bf(FA.z);              \
    p_[3] = f2bf(FA.w); p_[4] = f2bf(FB.x); p_[5] = f2bf(FB.y);              \
    p_[6] = f2bf(FB.z); p_[7] = f2bf(FB.w);                                  \
    *(bf16x8*)(DST) = p_;                                                    \
  }

#define FWRITE(BUF)                                      \
  {                                                      \
    CVT8(&Al[BUF][srow][sw8], ra0, ra1);                 \
    CVT8(&Al[BUF][srow + 64][sw8], ra2, ra3);            \
    CVT8(&Bl[BUF][srow][sw8], rb0, rb1);                 \
    CVT8(&Bl[BUF][srow + 64][sw8], rb2, rb3);            \
  }

  const int lane = tid & 63;
  const int w = tid >> 6;
  const int wr64 = (w >> 1) * 64;
  const int wc64 = (w & 1) * 64;
  const int fr = lane & 15;
  const int fkb_sw = (((lane >> 4) ^ ((fr >> 1) & 3))) * 8;

  f32x4 acc[4][4];
#pragma unroll
  for (int i = 0; i < 4; i++)
#pragma unroll
    for (int j = 0; j < 4; j++)
#pragma unroll
      for (int r = 0; r < 4; r++) acc[i][j][r] = 0.f;

  FLOADS(0);
  FWRITE(0);
  __syncthreads();

  const int NT = KD / GBK;
  for (int kt = 0; kt < NT; kt++) {
    const int cur = kt & 1;
    if (kt + 1 < NT) FLOADS(kt + 1);

    bf16x8 af[4], bg[4];
#pragma unroll
    for (int i = 0; i < 4; i++)
      af[i] = *(const bf16x8*)&Al[cur][wr64 + i * 16 + fr][fkb_sw];
#pragma unroll
    for (int j = 0; j < 4; j++)
      bg[j] = *(const bf16x8*)&Bl[cur][wc64 + j * 16 + fr][fkb_sw];

#pragma unroll
    for (int i = 0; i < 4; i++)
#pragma unroll
      for (int j = 0; j < 4; j++)
        acc[i][j] = __builtin_amdgcn_mfma_f32_16x16x32_bf16(af[i], bg[j], acc[i][j], 0, 0, 0);

    if (kt + 1 < NT) FWRITE(cur ^ 1);
    __syncthreads();
  }

  const int er = (lane >> 4) * 4;
  const int ec = lane & 15;
  emit_cands(acc, m0, n0, wr64, wc64, er, ec, cnt, lists, cap);
#undef FLOADS
#undef CVT8
#undef FWRITE
}

// ============ Select + decode, WAVE-PER-ROW + key-packed narrow (R12, banked) ====
// R14: CAND_NEED 48 -> 40 (saves 8 rows x 3KB x 8192 = ~200 MB of Wenc reads;
// margin rank-32->40 ~0.022 >> approx-path noise ~0.003 worst-case).
__global__ __launch_bounds__(256) void select_decode(const int* __restrict__ cnt,
                                                     const unsigned* __restrict__ lists,
                                                     int cap,
                                                     const float* __restrict__ X,
                                                     const float* __restrict__ Wenc,
                                                     const ushort_t* __restrict__ WdTb,
                                                     const float* __restrict__ Wdec,
                                                     int use_wdt,
                                                     float* __restrict__ Z,
                                                     float* __restrict__ Xhat) {
  __shared__ float xrow[4][KD];
  __shared__ unsigned keys[4][512];
  __shared__ int s48_j[4][CAND_NEED];
  __shared__ float s48_v[4][CAND_NEED];
  __shared__ int sel_j[4][TOPK];
  __shared__ float sel_v[4][TOPK];

  const int tid = threadIdx.x;
  const int w = tid >> 6;
  const int lane = tid & 63;
  const int row = blockIdx.x * 4 + w;
  float* z = Z + (size_t)row * NL;

  // xrow load: 768 floats = 3 float4 per lane, coalesced
  {
    const float4* xs = (const float4*)(X + (size_t)row * KD);
    float4* xd = (float4*)xrow[w];
#pragma unroll
    for (int q = 0; q < 3; q++) xd[lane + 64 * q] = xs[lane + 64 * q];
  }

  const int n = cnt[row];
  const bool fb = (n < CAND_NEED) || (n > cap) || (n > 512);

  if (!fb) {
    for (int i = lane; i < n; i += 64)
      keys[w][i] = lists[(size_t)row * cap + i] ^ 0xFFFFu;
    // narrow: rank by key desc (== value desc, index asc); keep ranks < CAND_NEED
    for (int i = lane; i < n; i += 64) {
      unsigned ki = keys[w][i];
      int r = 0;
      for (int c = 0; c < n; c++) r += (int)(keys[w][c] > ki);
      if (r < CAND_NEED) s48_j[w][r] = (int)((~ki) & 0xFFFFu);
    }
    // exact f32 recompute: ONE LANE per candidate, sequential k=0..767 fmaf
    // (bit-identical rounding chain — certified; DO NOT REORDER)
    if (lane < CAND_NEED) {
      const float4* wr4 = (const float4*)(Wenc + (size_t)s48_j[w][lane] * KD);
      float s = 0.f;
#pragma unroll 8
      for (int k4 = 0; k4 < KD / 4; k4++) {
        float4 wv = wr4[k4];
        s = fmaf(xrow[w][4 * k4 + 0], wv.x, s);
        s = fmaf(xrow[w][4 * k4 + 1], wv.y, s);
        s = fmaf(xrow[w][4 * k4 + 2], wv.z, s);
        s = fmaf(xrow[w][4 * k4 + 3], wv.w, s);
      }
      s48_v[w][lane] = s;
    }
    // z-zero, whole wave, non-temporal (never re-read)
    {
      const f32x4 zf = {0.f, 0.f, 0.f, 0.f};
      f32x4* z4 = (f32x4*)z;
      for (int i = lane; i < NL / 4; i += 64)
        __builtin_nontemporal_store(zf, z4 + i);
    }
    // exact top-32 by (value desc, index asc)
    if (lane < CAND_NEED) {
      float vi = s48_v[w][lane];
      int ji = s48_j[w][lane];
      int r = 0;
      for (int c = 0; c < CAND_NEED; c++) {
        float vc = s48_v[w][c];
        r += (int)((vc > vi) || (vc == vi && s48_j[w][c] < ji));
      }
      if (r < TOPK) { sel_j[w][r] = ji; sel_v[w][r] = fmaxf(vi, 0.f); }
    }
    // drain z-zero stores before scattering winners into the same row
    asm volatile("s_waitcnt vmcnt(0)" ::: "memory");
    if (lane < TOPK) z[sel_j[w][lane]] = sel_v[w][lane];
  } else {
    // ---- rare exact fallback (n stats make this ~never): dense per-wave
    for (int j = lane; j < NL; j += 64) {
      const float* wr = Wenc + (size_t)j * KD;
      float s = 0.f;
      for (int k = 0; k < KD; k++) s = fmaf(xrow[w][k], wr[k], s);
      z[j] = fmaxf(s, 0.f);
    }
    asm volatile("s_waitcnt vmcnt(0)" ::: "memory");
    for (int t = 0; t < TOPK; t++) {
      float bm = -1.f;
      int bi = NL;
      for (int j = lane; j < NL; j += 64) {
        float v = z[j];
        if (v > bm || (v == bm && j < bi)) { bm = v; bi = j; }
      }
#pragma unroll
      for (int off = 32; off > 0; off >>= 1) {
        float vo = __shfl_down(bm, off);
        int io = __shfl_down(bi, off);
        if (vo > bm || (vo == bm && io < bi)) { bm = vo; bi = io; }
      }
      bm = __shfl(bm, 0);
      bi = __shfl(bi, 0);
      if (lane == 0) {
        sel_j[w][t] = bi;
        sel_v[w][t] = bm;
        z[bi] = -1.f;  // sentinel below any relu'd value
      }
      asm volatile("s_waitcnt vmcnt(0)" ::: "memory");
    }
    for (int j = lane; j < NL; j += 64) z[j] = 0.f;
    asm volatile("s_waitcnt vmcnt(0)" ::: "memory");
    if (lane < TOPK) z[sel_j[w][lane]] = sel_v[w][lane];
  }

  // ---- fused decode, per-wave: lane owns 12 outputs d = q*128 + lane*2 (+1)
  float alo[6], ahi[6];
#pragma unroll
  for (int q = 0; q < 6; q++) { alo[q] = 0.f; ahi[q] = 0.f; }
  if (use_wdt) {
    for (int t = 0; t < TOPK; t++) {
      float v = sel_v[w][t];
      const unsigned* wr = (const unsigned*)(WdTb + (size_t)sel_j[w][t] * KD);
#pragma unroll
      for (int q = 0; q < 6; q++) {
        unsigned u = wr[q * 64 + lane];
        alo[q] = fmaf(v, bf2f((ushort_t)(u & 0xffffu)), alo[q]);
        ahi[q] = fmaf(v, bf2f((ushort_t)(u >> 16)), ahi[q]);
      }
    }
  } else {
    for (int t = 0; t < TOPK; t++) {
      float v = sel_v[w][t];
      const float* wc = Wdec + sel_j[w][t];
#pragma unroll
      for (int q = 0; q < 6; q++) {
        int d = q * 128 + lane * 2;
        alo[q] = fmaf(v, wc[(size_t)d * NL], alo[q]);
        ahi[q] = fmaf(v, wc[(size_t)(d + 1) * NL], ahi[q]);
      }
    }
  }
  float* xo = Xhat + (size_t)row * KD;
#pragma unroll
  for (int q = 0; q < 6; q++) {
    f32x2 st = {alo[q], ahi[q]};
    __builtin_nontemporal_store(st, (f32x2*)(xo + q * 128 + lane * 2));
  }
}

// ============ launch ============
extern "C" void kernel_launch(void* const* d_in, const int* in_sizes, int n_in,
                              void* d_out, int out_size, void* d_ws, size_t ws_size,
                              hipStream_t stream) {
  const float* x = (const float*)d_in[0];
  const float* Wenc = (const float*)d_in[1];
  const float* Wdec = (const float*)d_in[2];
  // d_in[3] is k (always 32 for this problem)

  float* xhat = (float*)d_out;
  float* z = (float*)d_out + (size_t)MB * KD;

  const size_t cnt_b = (size_t)MB * sizeof(int);              // 32 KB
  const size_t wsh_b = (size_t)NL * KD * sizeof(ushort_t);    // 25.2 MB (Wb, then WdTb)
  const size_t xb_b = (size_t)MB * KD * sizeof(ushort_t);     // 12.6 MB
  const size_t entry = sizeof(unsigned);                      // 4 B packed list entries

  char* ws = (char*)d_ws;
  int* cnt = (int*)ws;
  size_t off = cnt_b;

  int use_pre = 0, use_wdt = 0, cap = 1;
  ushort_t* Wsh = nullptr;
  ushort_t* Xb = nullptr;
  unsigned* lists = nullptr;

  if (ws_size >= cnt_b + wsh_b + xb_b + (size_t)MB * entry * CAP_MIN) {
    // tier A: bf16 global_load_lds GEMM; Wsh time-shared (Wb during GEMM, WdTb after)
    use_pre = 1; use_wdt = 1;
    Wsh = (ushort_t*)(ws + off); off += wsh_b;
    Xb = (ushort_t*)(ws + off); off += xb_b;
    lists = (unsigned*)(ws + off);
    size_t c = (ws_size - off) / ((size_t)MB * entry);
    cap = (int)(c > 512 ? 512 : c);
  } else if (ws_size >= cnt_b + wsh_b + (size_t)MB * entry * CAP_MIN) {
    // tier B: f32 GEMM with inline cvt; plain WdTb decode
    use_wdt = 1;
    Wsh = (ushort_t*)(ws + off); off += wsh_b;
    lists = (unsigned*)(ws + off);
    size_t c = (ws_size - off) / ((size_t)MB * entry);
    cap = (int)(c > 512 ? 512 : c);
  } else {
    // tier C: degraded — strided Wdec decode; whatever list fits (fb catches overflow)
    lists = (unsigned*)(ws + off);
    size_t avail = (ws_size > off) ? (ws_size - off) : 0;
    size_t c = avail / ((size_t)MB * entry);
    cap = (int)(c > 512 ? 512 : c);
    if (cap < 1) cap = 1;
  }

  if (use_pre) {
    // fused cvt for X + Wenc, with cnt zeroing folded in (blocks 0-31)
    int nx8 = MB * KD / 8, nw8 = NL * KD / 8;   // 786432, 1572864
    int nblk = nx8 / 256 + (nw8 + 255) / 256;   // 3072 + 6144
    cvt_both<<<nblk, 256, 0, stream>>>(x, Xb, nx8, Wenc, Wsh, nw8, cnt);
    encoder_gemm_pre2<<<(MB / GBM) * (NL / GBN), 256, 0, stream>>>(Xb, Wsh, cnt, lists, cap);
    // transpose AFTER the GEMM: Wsh is reused (stream-serialized, so no race)
    dim3 g(NL / 32, KD / 32);
    transpose_wdec<<<g, dim3(32, 8), 0, stream>>>(Wdec, Wsh);
  } else {
    hipMemsetAsync(cnt, 0, cnt_b, stream);
    if (use_wdt) {
      dim3 g(NL / 32, KD / 32);
      transpose_wdec<<<g, dim3(32, 8), 0, stream>>>(Wdec, Wsh);
    }
    encoder_gemm_f32<<<(MB / GBM) * (NL / GBN), 256, 0, stream>>>(x, Wenc, cnt, lists, cap);
  }
  select_decode<<<MB / 4, 256, 0, stream>>>(cnt, lists, cap, x, Wenc, Wsh, Wdec, use_wdt,
                                            z, xhat);
}